// Round 1
// baseline (181.669 us; speedup 1.0000x reference)
//
#include <hip/hip_runtime.h>
#include <hip/hip_bf16.h>

#define T_SEQ 2048
#define BATCH 2
#define DMODEL 512
#define NHEAD 8
#define DHEAD 64
#define DVAL 64
#define BH 16
#define CHUNK 64
#define NCHUNK 32
#define MROWS 4096   // BATCH*T_SEQ

typedef __bf16 bf16;
typedef __bf16 bf16x8 __attribute__((ext_vector_type(8)));
typedef __bf16 bf16x4 __attribute__((ext_vector_type(4)));
typedef float f32x4 __attribute__((ext_vector_type(4)));

// ---------------- kernel 0: fp32 -> bf16 conversion ----------------
__global__ void k_convert(const float* __restrict__ x,
                          const float* __restrict__ wq,
                          const float* __restrict__ wk,
                          const float* __restrict__ wv,
                          const float* __restrict__ wo,
                          bf16* __restrict__ x_bf,
                          bf16* __restrict__ wqkv_bf,
                          bf16* __restrict__ wo_bf) {
  const int W = DMODEL * DMODEL;
  int stride = gridDim.x * blockDim.x;
  int i0 = blockIdx.x * blockDim.x + threadIdx.x;
  for (int i = i0; i < MROWS * DMODEL; i += stride) x_bf[i] = (bf16)x[i];
  for (int i = i0; i < W; i += stride) {
    wqkv_bf[i]         = (bf16)wq[i];
    wqkv_bf[W + i]     = (bf16)wk[i];
    wqkv_bf[2 * W + i] = (bf16)wv[i];
    wo_bf[i]           = (bf16)wo[i];
  }
}

// ---------------- kernel 1: fused QKV projection (bf16 MFMA) ----------------
// C[m,n] = sum_k x[m,k] * Wqkv[n,k];  n<512 -> Q (elu+1), <1024 -> K (elu+1), else V
__global__ __launch_bounds__(256) void k_qkv(const bf16* __restrict__ x_bf,
                                             const bf16* __restrict__ w_bf,
                                             bf16* __restrict__ Q,
                                             bf16* __restrict__ K,
                                             bf16* __restrict__ V) {
  int wave = threadIdx.x >> 6, lane = threadIdx.x & 63;
  int c = lane & 15, quad = lane >> 4;
  int m0 = blockIdx.x * 64 + wave * 16;
  int n0 = blockIdx.y * 64;
  f32x4 acc[4] = {};
  const bf16* ap = x_bf + (size_t)(m0 + c) * DMODEL + quad * 8;
  const bf16* bp = w_bf + (size_t)(n0 + c) * DMODEL + quad * 8;
  for (int k0 = 0; k0 < DMODEL; k0 += 32) {
    bf16x8 a = *(const bf16x8*)(ap + k0);
#pragma unroll
    for (int f = 0; f < 4; f++) {
      bf16x8 b = *(const bf16x8*)(bp + (size_t)f * 16 * DMODEL + k0);
      acc[f] = __builtin_amdgcn_mfma_f32_16x16x32_bf16(a, b, acc[f], 0, 0, 0);
    }
  }
#pragma unroll
  for (int f = 0; f < 4; f++) {
    int n = n0 + f * 16 + c;
#pragma unroll
    for (int r = 0; r < 4; r++) {
      int m = m0 + quad * 4 + r;
      float v = acc[f][r];
      if (n < 1024) v = (v > 0.f) ? (v + 1.f) : __expf(v);  // phi = elu+1
      bf16 o = (bf16)v;
      if (n < 512)       Q[(size_t)m * 512 + n] = o;
      else if (n < 1024) K[(size_t)m * 512 + (n - 512)] = o;
      else               V[(size_t)m * 512 + (n - 1024)] = o;
    }
  }
}

// ---------------- kernel 2: per-chunk KV outer-product sums + z sums ----------------
__global__ __launch_bounds__(256) void k_chunksum(const bf16* __restrict__ K,
                                                  const bf16* __restrict__ V,
                                                  float* __restrict__ KVs,
                                                  float* __restrict__ zs) {
  __shared__ float Kc[CHUNK][DHEAD + 1];
  __shared__ float Vc[CHUNK][DVAL + 1];
  int chunk = blockIdx.x, bh = blockIdx.y;
  int b = bh >> 3, h = bh & 7;
  int tid = threadIdx.x;
  int rowbase = b * T_SEQ + chunk * CHUNK;
#pragma unroll
  for (int rep = 0; rep < 4; rep++) {
    int idx = tid + rep * 256;
    int r = idx >> 4, c4 = (idx & 15) * 4;
    bf16x4 k4 = *(const bf16x4*)(K + (size_t)(rowbase + r) * 512 + h * 64 + c4);
    bf16x4 v4 = *(const bf16x4*)(V + (size_t)(rowbase + r) * 512 + h * 64 + c4);
#pragma unroll
    for (int u = 0; u < 4; u++) {
      Kc[r][c4 + u] = (float)k4[u];
      Vc[r][c4 + u] = (float)v4[u];
    }
  }
  __syncthreads();
  int tx = tid & 15, ty = tid >> 4;
  float acc[4][4] = {};
  for (int t = 0; t < CHUNK; t++) {
    float a[4], bb[4];
#pragma unroll
    for (int ii = 0; ii < 4; ii++) a[ii] = Kc[t][ty * 4 + ii];
#pragma unroll
    for (int jj = 0; jj < 4; jj++) bb[jj] = Vc[t][tx * 4 + jj];
#pragma unroll
    for (int ii = 0; ii < 4; ii++)
#pragma unroll
      for (int jj = 0; jj < 4; jj++) acc[ii][jj] += a[ii] * bb[jj];
  }
  float* out = KVs + (size_t)(bh * NCHUNK + chunk) * DHEAD * DVAL;
#pragma unroll
  for (int ii = 0; ii < 4; ii++)
#pragma unroll
    for (int jj = 0; jj < 4; jj++)
      out[(ty * 4 + ii) * DVAL + tx * 4 + jj] = acc[ii][jj];
  if (tid < DHEAD) {
    float s = 0.f;
    for (int t = 0; t < CHUNK; t++) s += Kc[t][tid];
    zs[(size_t)(bh * NCHUNK + chunk) * DHEAD + tid] = s;
  }
}

// ---------------- kernel 3: exclusive prefix scan over chunks (in-place) ----------------
__global__ void k_scan(float* __restrict__ KVs, float* __restrict__ zs) {
  int bh = blockIdx.y;
  int e = blockIdx.x * 256 + threadIdx.x;   // 0..4095
  float run = 0.f;
  for (int cc = 0; cc < NCHUNK; cc++) {
    float* p = KVs + (size_t)(bh * NCHUNK + cc) * DHEAD * DVAL + e;
    float v = *p; *p = run; run += v;
  }
  if (blockIdx.x == 0 && threadIdx.x < DHEAD) {
    float runz = 0.f;
    for (int cc = 0; cc < NCHUNK; cc++) {
      float* p = zs + (size_t)(bh * NCHUNK + cc) * DHEAD + threadIdx.x;
      float v = *p; *p = runz; runz += v;
    }
  }
}

// ---------------- kernel 4: intra-chunk causal attention ----------------
__global__ __launch_bounds__(256) void k_intra(const bf16* __restrict__ Q,
                                               const bf16* __restrict__ K,
                                               const bf16* __restrict__ V,
                                               const float* __restrict__ KVs,
                                               const float* __restrict__ zs,
                                               bf16* __restrict__ O) {
  __shared__ float R0[CHUNK][DHEAD + 1];   // Qc
  __shared__ float R1[CHUNK][CHUNK + 1];   // Kc, then A = tril(Q K^T)
  __shared__ float R2[CHUNK][DVAL + 1];    // S_prefix, then Vc
  __shared__ float zpre[DHEAD];
  __shared__ float den[CHUNK];

  int chunk = blockIdx.x, bh = blockIdx.y;
  int b = bh >> 3, h = bh & 7;
  int tid = threadIdx.x;
  int rowbase = b * T_SEQ + chunk * CHUNK;
  const float* Sp = KVs + (size_t)(bh * NCHUNK + chunk) * DHEAD * DVAL;

#pragma unroll
  for (int rep = 0; rep < 4; rep++) {
    int idx = tid + rep * 256;
    int r = idx >> 4, c4 = (idx & 15) * 4;
    bf16x4 q4 = *(const bf16x4*)(Q + (size_t)(rowbase + r) * 512 + h * 64 + c4);
    bf16x4 k4 = *(const bf16x4*)(K + (size_t)(rowbase + r) * 512 + h * 64 + c4);
#pragma unroll
    for (int u = 0; u < 4; u++) {
      R0[r][c4 + u] = (float)q4[u];
      R1[r][c4 + u] = (float)k4[u];
      R2[r][c4 + u] = Sp[r * DVAL + c4 + u];
    }
  }
  if (tid < DHEAD) zpre[tid] = zs[(size_t)(bh * NCHUNK + chunk) * DHEAD + tid];
  __syncthreads();

  int tx = tid & 15, ty = tid >> 4;
  // Phase A: A[t][s] = Q[t].K[s], causal-masked
  float Ar[4][4] = {};
  for (int k = 0; k < DHEAD; k++) {
    float a[4], bb[4];
#pragma unroll
    for (int ii = 0; ii < 4; ii++) a[ii] = R0[ty * 4 + ii][k];
#pragma unroll
    for (int jj = 0; jj < 4; jj++) bb[jj] = R1[tx * 4 + jj][k];
#pragma unroll
    for (int ii = 0; ii < 4; ii++)
#pragma unroll
      for (int jj = 0; jj < 4; jj++) Ar[ii][jj] += a[ii] * bb[jj];
  }
#pragma unroll
  for (int ii = 0; ii < 4; ii++)
#pragma unroll
    for (int jj = 0; jj < 4; jj++)
      if (tx * 4 + jj > ty * 4 + ii) Ar[ii][jj] = 0.f;
  __syncthreads();                       // all Kc reads done
#pragma unroll
  for (int ii = 0; ii < 4; ii++)
#pragma unroll
    for (int jj = 0; jj < 4; jj++) R1[ty * 4 + ii][tx * 4 + jj] = Ar[ii][jj];
  __syncthreads();

  // den[t] = rowsum(A[t]) + Q[t].z_prefix
  if (tid < CHUNK) {
    float s = 0.f;
    for (int ss = 0; ss < CHUNK; ss++) s += R1[tid][ss];
    for (int k = 0; k < DHEAD; k++) s += R0[tid][k] * zpre[k];
    den[tid] = fmaxf(s, 1e-6f);
  }

  // O init: Q . S_prefix
  float oacc[4][4] = {};
  for (int k = 0; k < DHEAD; k++) {
    float a[4], bb[4];
#pragma unroll
    for (int ii = 0; ii < 4; ii++) a[ii] = R0[ty * 4 + ii][k];
#pragma unroll
    for (int jj = 0; jj < 4; jj++) bb[jj] = R2[k][tx * 4 + jj];
#pragma unroll
    for (int ii = 0; ii < 4; ii++)
#pragma unroll
      for (int jj = 0; jj < 4; jj++) oacc[ii][jj] += a[ii] * bb[jj];
  }
  __syncthreads();                       // S_prefix reads + den writes done
  // load Vc over S_prefix
#pragma unroll
  for (int rep = 0; rep < 4; rep++) {
    int idx = tid + rep * 256;
    int r = idx >> 4, c4 = (idx & 15) * 4;
    bf16x4 v4 = *(const bf16x4*)(V + (size_t)(rowbase + r) * 512 + h * 64 + c4);
#pragma unroll
    for (int u = 0; u < 4; u++) R2[r][c4 + u] = (float)v4[u];
  }
  __syncthreads();
  // O += A . V
  for (int s = 0; s < CHUNK; s++) {
    float a[4], bb[4];
#pragma unroll
    for (int ii = 0; ii < 4; ii++) a[ii] = R1[ty * 4 + ii][s];
#pragma unroll
    for (int jj = 0; jj < 4; jj++) bb[jj] = R2[s][tx * 4 + jj];
#pragma unroll
    for (int ii = 0; ii < 4; ii++)
#pragma unroll
      for (int jj = 0; jj < 4; jj++) oacc[ii][jj] += a[ii] * bb[jj];
  }
#pragma unroll
  for (int ii = 0; ii < 4; ii++) {
    int t = ty * 4 + ii;
    float d = den[t];
#pragma unroll
    for (int jj = 0; jj < 4; jj++) {
      float val = oacc[ii][jj] / d;
      O[(size_t)(rowbase + t) * 512 + h * 64 + tx * 4 + jj] = (bf16)val;
    }
  }
}

// ---------------- kernel 5: output projection (bf16 MFMA, fp32 out) ----------------
__global__ __launch_bounds__(256) void k_out(const bf16* __restrict__ O,
                                             const bf16* __restrict__ w_bf,
                                             float* __restrict__ out) {
  int wave = threadIdx.x >> 6, lane = threadIdx.x & 63;
  int c = lane & 15, quad = lane >> 4;
  int m0 = blockIdx.x * 64 + wave * 16;
  int n0 = blockIdx.y * 64;
  f32x4 acc[4] = {};
  const bf16* ap = O + (size_t)(m0 + c) * DMODEL + quad * 8;
  const bf16* bp = w_bf + (size_t)(n0 + c) * DMODEL + quad * 8;
  for (int k0 = 0; k0 < DMODEL; k0 += 32) {
    bf16x8 a = *(const bf16x8*)(ap + k0);
#pragma unroll
    for (int f = 0; f < 4; f++) {
      bf16x8 b = *(const bf16x8*)(bp + (size_t)f * 16 * DMODEL + k0);
      acc[f] = __builtin_amdgcn_mfma_f32_16x16x32_bf16(a, b, acc[f], 0, 0, 0);
    }
  }
#pragma unroll
  for (int f = 0; f < 4; f++) {
    int n = n0 + f * 16 + c;
#pragma unroll
    for (int r = 0; r < 4; r++) {
      int m = m0 + quad * 4 + r;
      out[(size_t)m * DMODEL + n] = acc[f][r];
    }
  }
}

extern "C" void kernel_launch(void* const* d_in, const int* in_sizes, int n_in,
                              void* d_out, int out_size, void* d_ws, size_t ws_size,
                              hipStream_t stream) {
  const float* x  = (const float*)d_in[0];
  const float* wq = (const float*)d_in[1];
  const float* wk = (const float*)d_in[2];
  const float* wv = (const float*)d_in[3];
  const float* wo = (const float*)d_in[4];
  float* out = (float*)d_out;

  char* p = (char*)d_ws;
  bf16* x_bf   = (bf16*)p; p += (size_t)MROWS * DMODEL * 2;          // 4 MB
  bf16* wqkv_b = (bf16*)p; p += (size_t)3 * DMODEL * DMODEL * 2;     // 1.5 MB
  bf16* wo_b   = (bf16*)p; p += (size_t)DMODEL * DMODEL * 2;         // 0.5 MB
  bf16* Qb     = (bf16*)p; p += (size_t)MROWS * 512 * 2;             // 4 MB
  bf16* Kb     = (bf16*)p; p += (size_t)MROWS * 512 * 2;             // 4 MB
  bf16* Vb     = (bf16*)p; p += (size_t)MROWS * 512 * 2;             // 4 MB
  bf16* Ob     = (bf16*)p; p += (size_t)MROWS * 512 * 2;             // 4 MB
  float* KVs   = (float*)p; p += (size_t)BH * NCHUNK * DHEAD * DVAL * 4;  // 8 MB
  float* zs    = (float*)p; p += (size_t)BH * NCHUNK * DHEAD * 4;    // 128 KB

  k_convert<<<2048, 256, 0, stream>>>(x, wq, wk, wv, wo, x_bf, wqkv_b, wo_b);
  k_qkv<<<dim3(MROWS / 64, (3 * DMODEL) / 64), 256, 0, stream>>>(x_bf, wqkv_b, Qb, Kb, Vb);
  k_chunksum<<<dim3(NCHUNK, BH), 256, 0, stream>>>(Kb, Vb, KVs, zs);
  k_scan<<<dim3((DHEAD * DVAL) / 256, BH), 256, 0, stream>>>(KVs, zs);
  k_intra<<<dim3(NCHUNK, BH), 256, 0, stream>>>(Qb, Kb, Vb, KVs, zs, Ob);
  k_out<<<dim3(MROWS / 64, DMODEL / 64), 256, 0, stream>>>(Ob, wo_b, out);
}

// Round 2
// 134.450 us; speedup vs baseline: 1.3512x; 1.3512x over previous
//
#include <hip/hip_runtime.h>
#include <hip/hip_bf16.h>

#define T_SEQ 2048
#define BATCH 2
#define DMODEL 512
#define NHEAD 8
#define DHEAD 64
#define DVAL 64
#define BH 16
#define CHUNK 64
#define NCHUNK 32
#define MROWS 4096   // BATCH*T_SEQ

typedef __bf16 bf16;
typedef __bf16 bf16x8 __attribute__((ext_vector_type(8)));
typedef __bf16 bf16x4 __attribute__((ext_vector_type(4)));
typedef float f32x4 __attribute__((ext_vector_type(4)));

__device__ inline void gload_lds16(const bf16* g, bf16* l) {
  __builtin_amdgcn_global_load_lds((const __attribute__((address_space(1))) void*)g,
                                   (__attribute__((address_space(3))) void*)l, 16, 0, 0);
}

// ---------------- kernel 0: fp32 -> bf16 conversion ----------------
__global__ void k_convert(const float* __restrict__ x,
                          const float* __restrict__ wq,
                          const float* __restrict__ wk,
                          const float* __restrict__ wv,
                          const float* __restrict__ wo,
                          bf16* __restrict__ x_bf,
                          bf16* __restrict__ wqkv_bf,
                          bf16* __restrict__ wo_bf) {
  const int W = DMODEL * DMODEL;
  int stride = gridDim.x * blockDim.x;
  int i0 = blockIdx.x * blockDim.x + threadIdx.x;
  for (int i = i0; i < MROWS * DMODEL; i += stride) x_bf[i] = (bf16)x[i];
  for (int i = i0; i < W; i += stride) {
    wqkv_bf[i]         = (bf16)wq[i];
    wqkv_bf[W + i]     = (bf16)wk[i];
    wqkv_bf[2 * W + i] = (bf16)wv[i];
    wo_bf[i]           = (bf16)wo[i];
  }
}

// ---------------- tiled MFMA GEMM: C[m,n] = sum_k A[m,k]*B[n,k] ----------------
// 128x128 block tile, BK=32, 4 waves (2x2), global_load_lds width=16 staging.
// EPI 0: QKV epilogue (elu+1 on n<1024, split into Q/K/V bf16)
// EPI 1: plain fp32 store to out
template <int EPI>
__global__ __launch_bounds__(256) void k_gemm(const bf16* __restrict__ A,
                                              const bf16* __restrict__ B,
                                              bf16* __restrict__ Q,
                                              bf16* __restrict__ K,
                                              bf16* __restrict__ V,
                                              float* __restrict__ out) {
  __shared__ bf16 As[128 * 32];
  __shared__ bf16 Bs[128 * 32];
  const int tid = threadIdx.x;
  const int wv = tid >> 6, lane = tid & 63;
  const int c = lane & 15, quad = lane >> 4;
  const int m_tile = blockIdx.x * 128, n_tile = blockIdx.y * 128;
  const int lrow = lane >> 2, lcol = (lane & 3) * 8;   // staging: 16 rows x 64B per wave-instr
  const bf16* Abase = A + (size_t)m_tile * DMODEL;
  const bf16* Bbase = B + (size_t)n_tile * DMODEL;
  const int wm = (wv >> 1) * 64, wn = (wv & 1) * 64;

  f32x4 acc[4][4] = {};

  for (int k0 = 0; k0 < DMODEL; k0 += 32) {
    if (k0) __syncthreads();
#pragma unroll
    for (int r = 0; r < 2; r++) {
      int t = wv + r * 4;                       // 16-row group 0..7
      const bf16* ga = Abase + (size_t)(t * 16 + lrow) * DMODEL + k0 + lcol;
      const bf16* gb = Bbase + (size_t)(t * 16 + lrow) * DMODEL + k0 + lcol;
      gload_lds16(ga, As + t * 16 * 32);
      gload_lds16(gb, Bs + t * 16 * 32);
    }
    __syncthreads();
    bf16x8 af[4], bfr[4];
#pragma unroll
    for (int i = 0; i < 4; i++)
      af[i] = *(const bf16x8*)(As + (wm + i * 16 + c) * 32 + quad * 8);
#pragma unroll
    for (int j = 0; j < 4; j++)
      bfr[j] = *(const bf16x8*)(Bs + (wn + j * 16 + c) * 32 + quad * 8);
#pragma unroll
    for (int i = 0; i < 4; i++)
#pragma unroll
      for (int j = 0; j < 4; j++)
        acc[i][j] = __builtin_amdgcn_mfma_f32_16x16x32_bf16(af[i], bfr[j], acc[i][j], 0, 0, 0);
  }

#pragma unroll
  for (int i = 0; i < 4; i++) {
#pragma unroll
    for (int j = 0; j < 4; j++) {
      int n = n_tile + wn + j * 16 + c;
#pragma unroll
      for (int r = 0; r < 4; r++) {
        int m = m_tile + wm + i * 16 + quad * 4 + r;
        float v = acc[i][j][r];
        if (EPI == 0) {
          if (n < 1024) v = (v > 0.f) ? (v + 1.f) : __expf(v);  // phi = elu+1
          bf16 o = (bf16)v;
          if (n < 512)       Q[(size_t)m * 512 + n] = o;
          else if (n < 1024) K[(size_t)m * 512 + (n - 512)] = o;
          else               V[(size_t)m * 512 + (n - 1024)] = o;
        } else {
          out[(size_t)m * DMODEL + n] = v;
        }
      }
    }
  }
}

// ---------------- kernel 2: per-chunk KV outer-product sums + z sums ----------------
__global__ __launch_bounds__(256) void k_chunksum(const bf16* __restrict__ K,
                                                  const bf16* __restrict__ V,
                                                  float* __restrict__ KVs,
                                                  float* __restrict__ zs) {
  __shared__ float Kc[CHUNK][DHEAD + 1];
  __shared__ float Vc[CHUNK][DVAL + 1];
  int chunk = blockIdx.x, bh = blockIdx.y;
  int b = bh >> 3, h = bh & 7;
  int tid = threadIdx.x;
  int rowbase = b * T_SEQ + chunk * CHUNK;
#pragma unroll
  for (int rep = 0; rep < 4; rep++) {
    int idx = tid + rep * 256;
    int r = idx >> 4, c4 = (idx & 15) * 4;
    bf16x4 k4 = *(const bf16x4*)(K + (size_t)(rowbase + r) * 512 + h * 64 + c4);
    bf16x4 v4 = *(const bf16x4*)(V + (size_t)(rowbase + r) * 512 + h * 64 + c4);
#pragma unroll
    for (int u = 0; u < 4; u++) {
      Kc[r][c4 + u] = (float)k4[u];
      Vc[r][c4 + u] = (float)v4[u];
    }
  }
  __syncthreads();
  int tx = tid & 15, ty = tid >> 4;
  float acc[4][4] = {};
  for (int t = 0; t < CHUNK; t++) {
    float a[4], bb[4];
#pragma unroll
    for (int ii = 0; ii < 4; ii++) a[ii] = Kc[t][ty * 4 + ii];
#pragma unroll
    for (int jj = 0; jj < 4; jj++) bb[jj] = Vc[t][tx * 4 + jj];
#pragma unroll
    for (int ii = 0; ii < 4; ii++)
#pragma unroll
      for (int jj = 0; jj < 4; jj++) acc[ii][jj] += a[ii] * bb[jj];
  }
  float* out = KVs + (size_t)(bh * NCHUNK + chunk) * DHEAD * DVAL;
#pragma unroll
  for (int ii = 0; ii < 4; ii++)
#pragma unroll
    for (int jj = 0; jj < 4; jj++)
      out[(ty * 4 + ii) * DVAL + tx * 4 + jj] = acc[ii][jj];
  if (tid < DHEAD) {
    float s = 0.f;
    for (int t = 0; t < CHUNK; t++) s += Kc[t][tid];
    zs[(size_t)(bh * NCHUNK + chunk) * DHEAD + tid] = s;
  }
}

// ---------------- kernel 3: exclusive prefix scan over chunks (in-place) ----------------
__global__ void k_scan(float* __restrict__ KVs, float* __restrict__ zs) {
  int bh = blockIdx.y;
  int e = blockIdx.x * 256 + threadIdx.x;   // 0..4095
  float run = 0.f;
  for (int cc = 0; cc < NCHUNK; cc++) {
    float* p = KVs + (size_t)(bh * NCHUNK + cc) * DHEAD * DVAL + e;
    float v = *p; *p = run; run += v;
  }
  if (blockIdx.x == 0 && threadIdx.x < DHEAD) {
    float runz = 0.f;
    for (int cc = 0; cc < NCHUNK; cc++) {
      float* p = zs + (size_t)(bh * NCHUNK + cc) * DHEAD + threadIdx.x;
      float v = *p; *p = runz; runz += v;
    }
  }
}

// ---------------- kernel 4: intra-chunk causal attention ----------------
__global__ __launch_bounds__(256) void k_intra(const bf16* __restrict__ Q,
                                               const bf16* __restrict__ K,
                                               const bf16* __restrict__ V,
                                               const float* __restrict__ KVs,
                                               const float* __restrict__ zs,
                                               bf16* __restrict__ O) {
  __shared__ float R0[CHUNK][DHEAD + 1];   // Qc
  __shared__ float R1[CHUNK][CHUNK + 1];   // Kc, then A = tril(Q K^T)
  __shared__ float R2[CHUNK][DVAL + 1];    // S_prefix, then Vc
  __shared__ float zpre[DHEAD];
  __shared__ float den[CHUNK];

  int chunk = blockIdx.x, bh = blockIdx.y;
  int b = bh >> 3, h = bh & 7;
  int tid = threadIdx.x;
  int rowbase = b * T_SEQ + chunk * CHUNK;
  const float* Sp = KVs + (size_t)(bh * NCHUNK + chunk) * DHEAD * DVAL;

#pragma unroll
  for (int rep = 0; rep < 4; rep++) {
    int idx = tid + rep * 256;
    int r = idx >> 4, c4 = (idx & 15) * 4;
    bf16x4 q4 = *(const bf16x4*)(Q + (size_t)(rowbase + r) * 512 + h * 64 + c4);
    bf16x4 k4 = *(const bf16x4*)(K + (size_t)(rowbase + r) * 512 + h * 64 + c4);
#pragma unroll
    for (int u = 0; u < 4; u++) {
      R0[r][c4 + u] = (float)q4[u];
      R1[r][c4 + u] = (float)k4[u];
      R2[r][c4 + u] = Sp[r * DVAL + c4 + u];
    }
  }
  if (tid < DHEAD) zpre[tid] = zs[(size_t)(bh * NCHUNK + chunk) * DHEAD + tid];
  __syncthreads();

  int tx = tid & 15, ty = tid >> 4;
  // Phase A: A[t][s] = Q[t].K[s], causal-masked
  float Ar[4][4] = {};
  for (int k = 0; k < DHEAD; k++) {
    float a[4], bb[4];
#pragma unroll
    for (int ii = 0; ii < 4; ii++) a[ii] = R0[ty * 4 + ii][k];
#pragma unroll
    for (int jj = 0; jj < 4; jj++) bb[jj] = R1[tx * 4 + jj][k];
#pragma unroll
    for (int ii = 0; ii < 4; ii++)
#pragma unroll
      for (int jj = 0; jj < 4; jj++) Ar[ii][jj] += a[ii] * bb[jj];
  }
#pragma unroll
  for (int ii = 0; ii < 4; ii++)
#pragma unroll
    for (int jj = 0; jj < 4; jj++)
      if (tx * 4 + jj > ty * 4 + ii) Ar[ii][jj] = 0.f;
  __syncthreads();                       // all Kc reads done
#pragma unroll
  for (int ii = 0; ii < 4; ii++)
#pragma unroll
    for (int jj = 0; jj < 4; jj++) R1[ty * 4 + ii][tx * 4 + jj] = Ar[ii][jj];
  __syncthreads();

  // den[t] = rowsum(A[t]) + Q[t].z_prefix
  if (tid < CHUNK) {
    float s = 0.f;
    for (int ss = 0; ss < CHUNK; ss++) s += R1[tid][ss];
    for (int k = 0; k < DHEAD; k++) s += R0[tid][k] * zpre[k];
    den[tid] = fmaxf(s, 1e-6f);
  }

  // O init: Q . S_prefix
  float oacc[4][4] = {};
  for (int k = 0; k < DHEAD; k++) {
    float a[4], bb[4];
#pragma unroll
    for (int ii = 0; ii < 4; ii++) a[ii] = R0[ty * 4 + ii][k];
#pragma unroll
    for (int jj = 0; jj < 4; jj++) bb[jj] = R2[k][tx * 4 + jj];
#pragma unroll
    for (int ii = 0; ii < 4; ii++)
#pragma unroll
      for (int jj = 0; jj < 4; jj++) oacc[ii][jj] += a[ii] * bb[jj];
  }
  __syncthreads();                       // S_prefix reads + den writes done
  // load Vc over S_prefix
#pragma unroll
  for (int rep = 0; rep < 4; rep++) {
    int idx = tid + rep * 256;
    int r = idx >> 4, c4 = (idx & 15) * 4;
    bf16x4 v4 = *(const bf16x4*)(V + (size_t)(rowbase + r) * 512 + h * 64 + c4);
#pragma unroll
    for (int u = 0; u < 4; u++) R2[r][c4 + u] = (float)v4[u];
  }
  __syncthreads();
  // O += A . V
  for (int s = 0; s < CHUNK; s++) {
    float a[4], bb[4];
#pragma unroll
    for (int ii = 0; ii < 4; ii++) a[ii] = R1[ty * 4 + ii][s];
#pragma unroll
    for (int jj = 0; jj < 4; jj++) bb[jj] = R2[s][tx * 4 + jj];
#pragma unroll
    for (int ii = 0; ii < 4; ii++)
#pragma unroll
      for (int jj = 0; jj < 4; jj++) oacc[ii][jj] += a[ii] * bb[jj];
  }
#pragma unroll
  for (int ii = 0; ii < 4; ii++) {
    int t = ty * 4 + ii;
    float d = den[t];
#pragma unroll
    for (int jj = 0; jj < 4; jj++) {
      float val = oacc[ii][jj] / d;
      O[(size_t)(rowbase + t) * 512 + h * 64 + tx * 4 + jj] = (bf16)val;
    }
  }
}

extern "C" void kernel_launch(void* const* d_in, const int* in_sizes, int n_in,
                              void* d_out, int out_size, void* d_ws, size_t ws_size,
                              hipStream_t stream) {
  const float* x  = (const float*)d_in[0];
  const float* wq = (const float*)d_in[1];
  const float* wk = (const float*)d_in[2];
  const float* wv = (const float*)d_in[3];
  const float* wo = (const float*)d_in[4];
  float* out = (float*)d_out;

  char* p = (char*)d_ws;
  bf16* x_bf   = (bf16*)p; p += (size_t)MROWS * DMODEL * 2;          // 4 MB
  bf16* wqkv_b = (bf16*)p; p += (size_t)3 * DMODEL * DMODEL * 2;     // 1.5 MB
  bf16* wo_b   = (bf16*)p; p += (size_t)DMODEL * DMODEL * 2;         // 0.5 MB
  bf16* Qb     = (bf16*)p; p += (size_t)MROWS * 512 * 2;             // 4 MB
  bf16* Kb     = (bf16*)p; p += (size_t)MROWS * 512 * 2;             // 4 MB
  bf16* Vb     = (bf16*)p; p += (size_t)MROWS * 512 * 2;             // 4 MB
  bf16* Ob     = (bf16*)p; p += (size_t)MROWS * 512 * 2;             // 4 MB
  float* KVs   = (float*)p; p += (size_t)BH * NCHUNK * DHEAD * DVAL * 4;  // 8 MB
  float* zs    = (float*)p; p += (size_t)BH * NCHUNK * DHEAD * 4;    // 128 KB

  k_convert<<<2048, 256, 0, stream>>>(x, wq, wk, wv, wo, x_bf, wqkv_b, wo_b);
  k_gemm<0><<<dim3(MROWS / 128, (3 * DMODEL) / 128), 256, 0, stream>>>(
      x_bf, wqkv_b, Qb, Kb, Vb, nullptr);
  k_chunksum<<<dim3(NCHUNK, BH), 256, 0, stream>>>(Kb, Vb, KVs, zs);
  k_scan<<<dim3((DHEAD * DVAL) / 256, BH), 256, 0, stream>>>(KVs, zs);
  k_intra<<<dim3(NCHUNK, BH), 256, 0, stream>>>(Qb, Kb, Vb, KVs, zs, Ob);
  k_gemm<1><<<dim3(MROWS / 128, DMODEL / 128), 256, 0, stream>>>(
      Ob, wo_b, nullptr, nullptr, nullptr, out);
}

// Round 3
// 125.240 us; speedup vs baseline: 1.4506x; 1.0735x over previous
//
#include <hip/hip_runtime.h>
#include <hip/hip_bf16.h>

#define T_SEQ 2048
#define BATCH 2
#define DMODEL 512
#define NHEAD 8
#define DHEAD 64
#define DVAL 64
#define BH 16
#define CHUNK 64
#define NCHUNK 32
#define MROWS 4096   // BATCH*T_SEQ

typedef __bf16 bf16;
typedef __bf16 bf16x8 __attribute__((ext_vector_type(8)));
typedef __bf16 bf16x4 __attribute__((ext_vector_type(4)));
typedef float f32x4 __attribute__((ext_vector_type(4)));

__device__ inline void gload_lds16(const bf16* g, bf16* l) {
  __builtin_amdgcn_global_load_lds((const __attribute__((address_space(1))) void*)g,
                                   (__attribute__((address_space(3))) void*)l, 16, 0, 0);
}

// XOR-swizzled slot offset (in elements) for transposed 64x64 bf16 LDS tiles.
// Element (row, t) lives at row*64 + sw_t(row, t>>3) + (t&7).
// Keeps ds_read_b128 16B-aligned; both transpose-writes and fragment reads <=2-way.
__device__ inline int sw_t(int row, int g) {
  return ((g ^ (row & 7) ^ (row >> 3)) << 3);
}

// ---------------- kernel 0: fp32 -> bf16 conversion ----------------
__global__ void k_convert(const float* __restrict__ x,
                          const float* __restrict__ wq,
                          const float* __restrict__ wk,
                          const float* __restrict__ wv,
                          const float* __restrict__ wo,
                          bf16* __restrict__ x_bf,
                          bf16* __restrict__ wqkv_bf,
                          bf16* __restrict__ wo_bf) {
  const int W = DMODEL * DMODEL;
  int stride = gridDim.x * blockDim.x;
  int i0 = blockIdx.x * blockDim.x + threadIdx.x;
  for (int i = i0; i < MROWS * DMODEL; i += stride) x_bf[i] = (bf16)x[i];
  for (int i = i0; i < W; i += stride) {
    wqkv_bf[i]         = (bf16)wq[i];
    wqkv_bf[W + i]     = (bf16)wk[i];
    wqkv_bf[2 * W + i] = (bf16)wv[i];
    wo_bf[i]           = (bf16)wo[i];
  }
}

// ---------------- tiled MFMA GEMM: C[m,n] = sum_k A[m,k]*B[n,k] ----------------
template <int EPI>
__global__ __launch_bounds__(256) void k_gemm(const bf16* __restrict__ A,
                                              const bf16* __restrict__ B,
                                              bf16* __restrict__ Q,
                                              bf16* __restrict__ K,
                                              bf16* __restrict__ V,
                                              float* __restrict__ out) {
  __shared__ bf16 As[128 * 32];
  __shared__ bf16 Bs[128 * 32];
  const int tid = threadIdx.x;
  const int wv = tid >> 6, lane = tid & 63;
  const int c = lane & 15, quad = lane >> 4;
  const int m_tile = blockIdx.x * 128, n_tile = blockIdx.y * 128;
  const int lrow = lane >> 2, lcol = (lane & 3) * 8;
  const bf16* Abase = A + (size_t)m_tile * DMODEL;
  const bf16* Bbase = B + (size_t)n_tile * DMODEL;
  const int wm = (wv >> 1) * 64, wn = (wv & 1) * 64;

  f32x4 acc[4][4] = {};

  for (int k0 = 0; k0 < DMODEL; k0 += 32) {
    if (k0) __syncthreads();
#pragma unroll
    for (int r = 0; r < 2; r++) {
      int t = wv + r * 4;
      const bf16* ga = Abase + (size_t)(t * 16 + lrow) * DMODEL + k0 + lcol;
      const bf16* gb = Bbase + (size_t)(t * 16 + lrow) * DMODEL + k0 + lcol;
      gload_lds16(ga, As + t * 16 * 32);
      gload_lds16(gb, Bs + t * 16 * 32);
    }
    __syncthreads();
    bf16x8 af[4], bfr[4];
#pragma unroll
    for (int i = 0; i < 4; i++)
      af[i] = *(const bf16x8*)(As + (wm + i * 16 + c) * 32 + quad * 8);
#pragma unroll
    for (int j = 0; j < 4; j++)
      bfr[j] = *(const bf16x8*)(Bs + (wn + j * 16 + c) * 32 + quad * 8);
#pragma unroll
    for (int i = 0; i < 4; i++)
#pragma unroll
      for (int j = 0; j < 4; j++)
        acc[i][j] = __builtin_amdgcn_mfma_f32_16x16x32_bf16(af[i], bfr[j], acc[i][j], 0, 0, 0);
  }

#pragma unroll
  for (int i = 0; i < 4; i++) {
#pragma unroll
    for (int j = 0; j < 4; j++) {
      int n = n_tile + wn + j * 16 + c;
#pragma unroll
      for (int r = 0; r < 4; r++) {
        int m = m_tile + wm + i * 16 + quad * 4 + r;
        float v = acc[i][j][r];
        if (EPI == 0) {
          if (n < 1024) v = (v > 0.f) ? (v + 1.f) : __expf(v);  // phi = elu+1
          bf16 o = (bf16)v;
          if (n < 512)       Q[(size_t)m * 512 + n] = o;
          else if (n < 1024) K[(size_t)m * 512 + (n - 512)] = o;
          else               V[(size_t)m * 512 + (n - 1024)] = o;
        } else {
          out[(size_t)m * DMODEL + n] = v;
        }
      }
    }
  }
}

// ---------------- kernel 2: per-chunk S^T_c = V^T K (MFMA) + z_c ----------------
__global__ __launch_bounds__(256) void k_state(const bf16* __restrict__ K,
                                               const bf16* __restrict__ V,
                                               float* __restrict__ KVs,
                                               float* __restrict__ zsum) {
  __shared__ bf16 Kt[4096];   // Kt[i][t] swizzled
  __shared__ bf16 Vt[4096];   // Vt[j][t] swizzled
  int chunk = blockIdx.x, bh = blockIdx.y;
  int b = bh >> 3, h = bh & 7;
  int tid = threadIdx.x, lane = tid & 63, wv = tid >> 6;
  int rowbase = b * T_SEQ + chunk * CHUNK;

#pragma unroll
  for (int p = 0; p < 2; p++) {
    int r = p * 32 + (tid >> 3);
    int j0 = (tid & 7) * 8;
    bf16x8 kk = *(const bf16x8*)(K + (size_t)(rowbase + r) * 512 + h * 64 + j0);
    bf16x8 vvv = *(const bf16x8*)(V + (size_t)(rowbase + r) * 512 + h * 64 + j0);
#pragma unroll
    for (int u = 0; u < 8; u++) {
      int row = j0 + u;
      Kt[row * 64 + sw_t(row, r >> 3) + (r & 7)] = kk[u];
      Vt[row * 64 + sw_t(row, r >> 3) + (r & 7)] = vvv[u];
    }
  }
  __syncthreads();

  int c = lane & 15, quad = lane >> 4;
  f32x4 acc[4] = {};
#pragma unroll
  for (int ks = 0; ks < 2; ks++) {
    int ar = wv * 16 + c;
    bf16x8 a = *(const bf16x8*)(Vt + ar * 64 + sw_t(ar, ks * 4 + quad));
#pragma unroll
    for (int f = 0; f < 4; f++) {
      int br = f * 16 + c;
      bf16x8 bb = *(const bf16x8*)(Kt + br * 64 + sw_t(br, ks * 4 + quad));
      acc[f] = __builtin_amdgcn_mfma_f32_16x16x32_bf16(a, bb, acc[f], 0, 0, 0);
    }
  }
  float* op = KVs + ((size_t)(bh * NCHUNK + chunk) << 12);
#pragma unroll
  for (int f = 0; f < 4; f++)
#pragma unroll
    for (int r = 0; r < 4; r++)
      op[(wv * 16 + quad * 4 + r) * 64 + f * 16 + c] = acc[f][r];

  if (tid < 64) {
    float s = 0.f;
#pragma unroll
    for (int g = 0; g < 8; g++) {
      bf16x8 kr = *(const bf16x8*)(Kt + tid * 64 + sw_t(tid, g));
#pragma unroll
      for (int u = 0; u < 8; u++) s += (float)kr[u];
    }
    zsum[(size_t)(bh * NCHUNK + chunk) * 64 + tid] = s;
  }
}

// ---------------- kernel 3: fused prefix + intra-chunk attention (MFMA) ----------------
__global__ __launch_bounds__(256) void k_attn(const bf16* __restrict__ Q,
                                              const bf16* __restrict__ K,
                                              const bf16* __restrict__ V,
                                              const float* __restrict__ KVs,
                                              const float* __restrict__ zsum,
                                              bf16* __restrict__ O) {
  __shared__ bf16 Qs[4096];    // rows k-contig, slot g holds k-group g^(row&7)
  __shared__ bf16 Ks[4096];
  __shared__ bf16 Vt[4096];    // transposed, sw_t swizzle
  __shared__ bf16 As[4096];    // attention matrix rows, sw_t swizzle
  __shared__ bf16 Spre[4096];  // S^T_prefix rows [j][i], sw_t swizzle
  __shared__ float zp4[4][64];
  __shared__ float zpre[64], rsum[64], den[64];

  int chunk = blockIdx.x, bh = blockIdx.y;
  int b = bh >> 3, h = bh & 7;
  int tid = threadIdx.x, lane = tid & 63, wv = tid >> 6;
  int c = lane & 15, quad = lane >> 4;
  int rowbase = b * T_SEQ + chunk * CHUNK;

  // async stage Qs, Ks (XOR by row&7 so fragment reads are ~2-way)
#pragma unroll
  for (int p = 0; p < 2; p++) {
    int rbase = p * 32 + wv * 8;
    int r8 = lane >> 3, gp = lane & 7;
    const bf16* gq = Q + (size_t)(rowbase + rbase + r8) * 512 + h * 64 + ((gp ^ r8) << 3);
    const bf16* gk = K + (size_t)(rowbase + rbase + r8) * 512 + h * 64 + ((gp ^ r8) << 3);
    gload_lds16(gq, Qs + rbase * 64);
    gload_lds16(gk, Ks + rbase * 64);
  }

  // V load + transpose into Vt
#pragma unroll
  for (int p = 0; p < 2; p++) {
    int r = p * 32 + (tid >> 3);
    int j0 = (tid & 7) * 8;
    bf16x8 vvv = *(const bf16x8*)(V + (size_t)(rowbase + r) * 512 + h * 64 + j0);
#pragma unroll
    for (int u = 0; u < 8; u++) {
      int row = j0 + u;
      Vt[row * 64 + sw_t(row, r >> 3) + (r & 7)] = vvv[u];
    }
  }

  // prefix of chunk sums: this thread's 16 elements, fully parallel loads
  {
    float accp[16];
#pragma unroll
    for (int u = 0; u < 16; u++) accp[u] = 0.f;
    const float* base = KVs + ((size_t)(bh * NCHUNK) << 12) + tid * 16;
    for (int cc = 0; cc < chunk; cc++) {
      const float* pp = base + ((size_t)cc << 12);
#pragma unroll
      for (int q4 = 0; q4 < 4; q4++) {
        f32x4 v4 = *(const f32x4*)(pp + q4 * 4);
#pragma unroll
        for (int u = 0; u < 4; u++) accp[q4 * 4 + u] += v4[u];
      }
    }
    int j = tid >> 2, i0 = (tid & 3) * 16;
#pragma unroll
    for (int u = 0; u < 16; u++) {
      int i = i0 + u;
      Spre[j * 64 + sw_t(j, i >> 3) + (i & 7)] = (bf16)accp[u];
    }
  }

  // z prefix partials (per wave)
  {
    int i = tid & 63, qq = tid >> 6;
    float s = 0.f;
    for (int cc = qq; cc < chunk; cc += 4)
      s += zsum[(size_t)(bh * NCHUNK + cc) * 64 + i];
    zp4[qq][i] = s;
  }
  __syncthreads();  // B1: all LDS staged
  if (tid < 64) zpre[tid] = zp4[0][tid] + zp4[1][tid] + zp4[2][tid] + zp4[3][tid];

  // QK^T (all 4 n-frags; causal via ternary)
  f32x4 sacc[4] = {};
#pragma unroll
  for (int ks = 0; ks < 2; ks++) {
    int ar = 16 * wv + c;
    bf16x8 a = *(const bf16x8*)(Qs + ar * 64 + (((ks * 4 + quad) ^ (c & 7)) << 3));
#pragma unroll
    for (int j = 0; j < 4; j++) {
      int br = 16 * j + c;
      bf16x8 bb = *(const bf16x8*)(Ks + br * 64 + (((ks * 4 + quad) ^ (c & 7)) << 3));
      sacc[j] = __builtin_amdgcn_mfma_f32_16x16x32_bf16(a, bb, sacc[j], 0, 0, 0);
    }
  }

  // mask, rowsum, write As (covers all 64x64 incl. zeros above diagonal)
  float rs[4] = {0.f, 0.f, 0.f, 0.f};
#pragma unroll
  for (int j = 0; j < 4; j++) {
#pragma unroll
    for (int r = 0; r < 4; r++) {
      int t = 16 * wv + quad * 4 + r, s = 16 * j + c;
      float v = (s <= t) ? sacc[j][r] : 0.f;
      rs[r] += v;
      As[t * 64 + sw_t(t, s >> 3) + (s & 7)] = (bf16)v;
    }
  }
#pragma unroll
  for (int r = 0; r < 4; r++) {
    float v = rs[r];
    v += __shfl_xor(v, 1); v += __shfl_xor(v, 2);
    v += __shfl_xor(v, 4); v += __shfl_xor(v, 8);
    if (c == 0) rsum[16 * wv + quad * 4 + r] = v;
  }
  __syncthreads();  // B2: As, rsum, zpre visible

  // den[t] = max(rowsum + Q[t].z_pre, 1e-6)
  if (tid < 64) {
    float s = rsum[tid];
    int t7 = tid & 7;
#pragma unroll
    for (int kg = 0; kg < 8; kg++) {
      bf16x8 qv = *(const bf16x8*)(Qs + tid * 64 + ((kg ^ t7) << 3));
#pragma unroll
      for (int u = 0; u < 8; u++) s += (float)qv[u] * zpre[kg * 8 + u];
    }
    den[tid] = fmaxf(s, 1e-6f);
  }

  // O = Q.S_pre + A.V
  f32x4 oacc[4] = {};
#pragma unroll
  for (int ks = 0; ks < 2; ks++) {
    int ar = 16 * wv + c;
    bf16x8 aq = *(const bf16x8*)(Qs + ar * 64 + (((ks * 4 + quad) ^ (c & 7)) << 3));
    bf16x8 aa = *(const bf16x8*)(As + ar * 64 + sw_t(ar, ks * 4 + quad));
#pragma unroll
    for (int j = 0; j < 4; j++) {
      int br = 16 * j + c;
      bf16x8 bs = *(const bf16x8*)(Spre + br * 64 + sw_t(br, ks * 4 + quad));
      bf16x8 bv = *(const bf16x8*)(Vt + br * 64 + sw_t(br, ks * 4 + quad));
      oacc[j] = __builtin_amdgcn_mfma_f32_16x16x32_bf16(aq, bs, oacc[j], 0, 0, 0);
      oacc[j] = __builtin_amdgcn_mfma_f32_16x16x32_bf16(aa, bv, oacc[j], 0, 0, 0);
    }
  }
  __syncthreads();  // B3: den visible
#pragma unroll
  for (int r = 0; r < 4; r++) {
    int t = 16 * wv + quad * 4 + r;
    float rd = 1.f / den[t];
#pragma unroll
    for (int j = 0; j < 4; j++)
      O[(size_t)(rowbase + t) * 512 + h * 64 + 16 * j + c] = (bf16)(oacc[j][r] * rd);
  }
}

extern "C" void kernel_launch(void* const* d_in, const int* in_sizes, int n_in,
                              void* d_out, int out_size, void* d_ws, size_t ws_size,
                              hipStream_t stream) {
  const float* x  = (const float*)d_in[0];
  const float* wq = (const float*)d_in[1];
  const float* wk = (const float*)d_in[2];
  const float* wv = (const float*)d_in[3];
  const float* wo = (const float*)d_in[4];
  float* out = (float*)d_out;

  char* p = (char*)d_ws;
  bf16* x_bf   = (bf16*)p; p += (size_t)MROWS * DMODEL * 2;
  bf16* wqkv_b = (bf16*)p; p += (size_t)3 * DMODEL * DMODEL * 2;
  bf16* wo_b   = (bf16*)p; p += (size_t)DMODEL * DMODEL * 2;
  bf16* Qb     = (bf16*)p; p += (size_t)MROWS * 512 * 2;
  bf16* Kb     = (bf16*)p; p += (size_t)MROWS * 512 * 2;
  bf16* Vb     = (bf16*)p; p += (size_t)MROWS * 512 * 2;
  bf16* Ob     = (bf16*)p; p += (size_t)MROWS * 512 * 2;
  float* KVs   = (float*)p; p += (size_t)BH * NCHUNK * DHEAD * DVAL * 4;
  float* zs    = (float*)p; p += (size_t)BH * NCHUNK * DHEAD * 4;

  k_convert<<<2048, 256, 0, stream>>>(x, wq, wk, wv, wo, x_bf, wqkv_b, wo_b);
  k_gemm<0><<<dim3(MROWS / 128, (3 * DMODEL) / 128), 256, 0, stream>>>(
      x_bf, wqkv_b, Qb, Kb, Vb, nullptr);
  k_state<<<dim3(NCHUNK, BH), 256, 0, stream>>>(Kb, Vb, KVs, zs);
  k_attn<<<dim3(NCHUNK, BH), 256, 0, stream>>>(Qb, Kb, Vb, KVs, zs, Ob);
  k_gemm<1><<<dim3(MROWS / 128, DMODEL / 128), 256, 0, stream>>>(
      Ob, wo_b, nullptr, nullptr, nullptr, out);
}

// Round 4
// 119.909 us; speedup vs baseline: 1.5150x; 1.0445x over previous
//
#include <hip/hip_runtime.h>
#include <hip/hip_bf16.h>

#define T_SEQ 2048
#define BATCH 2
#define DMODEL 512
#define NHEAD 8
#define DHEAD 64
#define DVAL 64
#define BH 16
#define CHUNK 64
#define NCHUNK 32
#define MROWS 4096   // BATCH*T_SEQ

typedef __bf16 bf16;
typedef __bf16 bf16x8 __attribute__((ext_vector_type(8)));
typedef __bf16 bf16x4 __attribute__((ext_vector_type(4)));
typedef float f32x4 __attribute__((ext_vector_type(4)));

__device__ inline void gload_lds16(const bf16* g, bf16* l) {
  __builtin_amdgcn_global_load_lds((const __attribute__((address_space(1))) void*)g,
                                   (__attribute__((address_space(3))) void*)l, 16, 0, 0);
}

// XOR-swizzled slot offset (elements) for 64-col bf16 LDS tiles: element (row, k)
// with k-group g=k/8 lives at row*64 + ((g ^ (row&7) [^ row>>3 for transposed]) << 3).
__device__ inline int sw_t(int row, int g) {
  return ((g ^ (row & 7) ^ (row >> 3)) << 3);
}

// ---------------- kernel 0: fp32 -> bf16 conversion (vectorized) ----------------
__global__ __launch_bounds__(256) void k_convert(const float* __restrict__ x,
                          const float* __restrict__ wq,
                          const float* __restrict__ wk,
                          const float* __restrict__ wv,
                          const float* __restrict__ wo,
                          bf16* __restrict__ x_bf,
                          bf16* __restrict__ wqkv_bf,
                          bf16* __restrict__ wo_bf) {
  const int W = DMODEL * DMODEL;           // 262144
  int i = blockIdx.x * 256 + threadIdx.x;  // 0..524287 (grid 2048)
  {
    f32x4 v = ((const f32x4*)x)[i];
    bf16x4 o; o[0] = (bf16)v[0]; o[1] = (bf16)v[1]; o[2] = (bf16)v[2]; o[3] = (bf16)v[3];
    *(bf16x4*)(x_bf + (size_t)i * 4) = o;
  }
  if (i < W / 4) {
    f32x4 a = ((const f32x4*)wq)[i];
    f32x4 b = ((const f32x4*)wk)[i];
    f32x4 c = ((const f32x4*)wv)[i];
    f32x4 d = ((const f32x4*)wo)[i];
    bf16x4 oa, ob, oc, od;
#pragma unroll
    for (int u = 0; u < 4; u++) { oa[u] = (bf16)a[u]; ob[u] = (bf16)b[u]; oc[u] = (bf16)c[u]; od[u] = (bf16)d[u]; }
    *(bf16x4*)(wqkv_bf + (size_t)i * 4) = oa;
    *(bf16x4*)(wqkv_bf + W + (size_t)i * 4) = ob;
    *(bf16x4*)(wqkv_bf + 2 * W + (size_t)i * 4) = oc;
    *(bf16x4*)(wo_bf + (size_t)i * 4) = od;
  }
}

// ---------------- tiled MFMA GEMM: C[m,n] = sum_k A[m,k]*B[n,k] ----------------
// 128x128 tile, BK=64 (8 K-iters), XOR-swizzled LDS, global_load_lds width=16.
template <int EPI>
__global__ __launch_bounds__(256) void k_gemm(const bf16* __restrict__ A,
                                              const bf16* __restrict__ B,
                                              bf16* __restrict__ Q,
                                              bf16* __restrict__ K,
                                              bf16* __restrict__ V,
                                              float* __restrict__ out) {
  __shared__ bf16 As[128 * 64];
  __shared__ bf16 Bs[128 * 64];
  const int tid = threadIdx.x;
  const int wv = tid >> 6, lane = tid & 63;
  const int c = lane & 15, quad = lane >> 4;
  const int m_tile = blockIdx.x * 128, n_tile = blockIdx.y * 128;
  const int r8 = lane >> 3, gp = lane & 7;
  const bf16* Abase = A + (size_t)m_tile * DMODEL;
  const bf16* Bbase = B + (size_t)n_tile * DMODEL;
  const int wm = (wv >> 1) * 64, wn = (wv & 1) * 64;

  f32x4 acc[4][4] = {};

  for (int k0 = 0; k0 < DMODEL; k0 += 64) {
    if (k0) __syncthreads();
#pragma unroll
    for (int r = 0; r < 4; r++) {
      int t = wv * 4 + r;                       // 8-row group 0..15
      const bf16* ga = Abase + (size_t)(t * 8 + r8) * DMODEL + k0 + ((gp ^ r8) << 3);
      const bf16* gb = Bbase + (size_t)(t * 8 + r8) * DMODEL + k0 + ((gp ^ r8) << 3);
      gload_lds16(ga, As + t * 8 * 64);
      gload_lds16(gb, Bs + t * 8 * 64);
    }
    __syncthreads();
#pragma unroll
    for (int ks = 0; ks < 2; ks++) {
      bf16x8 af[4], bfr[4];
#pragma unroll
      for (int i = 0; i < 4; i++)
        af[i] = *(const bf16x8*)(As + (wm + i * 16 + c) * 64 + (((ks * 4 + quad) ^ (c & 7)) << 3));
#pragma unroll
      for (int j = 0; j < 4; j++)
        bfr[j] = *(const bf16x8*)(Bs + (wn + j * 16 + c) * 64 + (((ks * 4 + quad) ^ (c & 7)) << 3));
#pragma unroll
      for (int i = 0; i < 4; i++)
#pragma unroll
        for (int j = 0; j < 4; j++)
          acc[i][j] = __builtin_amdgcn_mfma_f32_16x16x32_bf16(af[i], bfr[j], acc[i][j], 0, 0, 0);
    }
  }

#pragma unroll
  for (int i = 0; i < 4; i++) {
#pragma unroll
    for (int j = 0; j < 4; j++) {
      int n = n_tile + wn + j * 16 + c;
#pragma unroll
      for (int r = 0; r < 4; r++) {
        int m = m_tile + wm + i * 16 + quad * 4 + r;
        float v = acc[i][j][r];
        if (EPI == 0) {
          if (n < 1024) v = (v > 0.f) ? (v + 1.f) : __expf(v);  // phi = elu+1
          bf16 o = (bf16)v;
          if (n < 512)       Q[(size_t)m * 512 + n] = o;
          else if (n < 1024) K[(size_t)m * 512 + (n - 512)] = o;
          else               V[(size_t)m * 512 + (n - 1024)] = o;
        } else {
          out[(size_t)m * DMODEL + n] = v;
        }
      }
    }
  }
}

// ---------------- kernel 2: per-chunk S^T_c = V^T K (MFMA, bf16 out) + z_c ----------------
__global__ __launch_bounds__(256) void k_state(const bf16* __restrict__ K,
                                               const bf16* __restrict__ V,
                                               bf16* __restrict__ KVs,
                                               float* __restrict__ zsum) {
  __shared__ bf16 Kt[4096];   // Kt[i][t] swizzled
  __shared__ bf16 Vt[4096];   // Vt[j][t] swizzled
  int chunk = blockIdx.x, bh = blockIdx.y;
  int b = bh >> 3, h = bh & 7;
  int tid = threadIdx.x, lane = tid & 63, wv = tid >> 6;
  int rowbase = b * T_SEQ + chunk * CHUNK;

#pragma unroll
  for (int p = 0; p < 2; p++) {
    int r = p * 32 + (tid >> 3);
    int j0 = (tid & 7) * 8;
    bf16x8 kk = *(const bf16x8*)(K + (size_t)(rowbase + r) * 512 + h * 64 + j0);
    bf16x8 vvv = *(const bf16x8*)(V + (size_t)(rowbase + r) * 512 + h * 64 + j0);
#pragma unroll
    for (int u = 0; u < 8; u++) {
      int row = j0 + u;
      Kt[row * 64 + sw_t(row, r >> 3) + (r & 7)] = kk[u];
      Vt[row * 64 + sw_t(row, r >> 3) + (r & 7)] = vvv[u];
    }
  }
  __syncthreads();

  int c = lane & 15, quad = lane >> 4;
  f32x4 acc[4] = {};
#pragma unroll
  for (int ks = 0; ks < 2; ks++) {
    int ar = wv * 16 + c;
    bf16x8 a = *(const bf16x8*)(Vt + ar * 64 + sw_t(ar, ks * 4 + quad));
#pragma unroll
    for (int f = 0; f < 4; f++) {
      int br = f * 16 + c;
      bf16x8 bb = *(const bf16x8*)(Kt + br * 64 + sw_t(br, ks * 4 + quad));
      acc[f] = __builtin_amdgcn_mfma_f32_16x16x32_bf16(a, bb, acc[f], 0, 0, 0);
    }
  }
  bf16* op = KVs + ((size_t)(bh * NCHUNK + chunk) << 12);
#pragma unroll
  for (int f = 0; f < 4; f++)
#pragma unroll
    for (int r = 0; r < 4; r++)
      op[(wv * 16 + quad * 4 + r) * 64 + f * 16 + c] = (bf16)acc[f][r];

  if (tid < 64) {
    float s = 0.f;
#pragma unroll
    for (int g = 0; g < 8; g++) {
      bf16x8 kr = *(const bf16x8*)(Kt + tid * 64 + sw_t(tid, g));
#pragma unroll
      for (int u = 0; u < 8; u++) s += (float)kr[u];
    }
    zsum[(size_t)(bh * NCHUNK + chunk) * 64 + tid] = s;
  }
}

// ---------------- kernel 3: fused prefix + intra-chunk attention (MFMA) ----------------
__global__ __launch_bounds__(256) void k_attn(const bf16* __restrict__ Q,
                                              const bf16* __restrict__ K,
                                              const bf16* __restrict__ V,
                                              const bf16* __restrict__ KVs,
                                              const float* __restrict__ zsum,
                                              bf16* __restrict__ O) {
  __shared__ bf16 Qs[4096];    // rows k-contig, slot g holds k-group g^(row&7)
  __shared__ bf16 Ks[4096];
  __shared__ bf16 Vt[4096];    // transposed, sw_t swizzle
  __shared__ bf16 As[4096];    // attention matrix rows, sw_t swizzle
  __shared__ bf16 Spre[4096];  // S^T_prefix rows [j][i], sw_t swizzle
  __shared__ float zp4[4][64];
  __shared__ float zpre[64], rsum[64], den[64];

  int chunk = blockIdx.x, bh = blockIdx.y;
  int b = bh >> 3, h = bh & 7;
  int tid = threadIdx.x, lane = tid & 63, wv = tid >> 6;
  int c = lane & 15, quad = lane >> 4;
  int rowbase = b * T_SEQ + chunk * CHUNK;

  // async stage Qs, Ks (XOR by row&7 so fragment reads are ~2-way)
#pragma unroll
  for (int p = 0; p < 2; p++) {
    int rbase = p * 32 + wv * 8;
    int r8 = lane >> 3, gp = lane & 7;
    const bf16* gq = Q + (size_t)(rowbase + rbase + r8) * 512 + h * 64 + ((gp ^ r8) << 3);
    const bf16* gk = K + (size_t)(rowbase + rbase + r8) * 512 + h * 64 + ((gp ^ r8) << 3);
    gload_lds16(gq, Qs + rbase * 64);
    gload_lds16(gk, Ks + rbase * 64);
  }

  // V load + transpose into Vt
#pragma unroll
  for (int p = 0; p < 2; p++) {
    int r = p * 32 + (tid >> 3);
    int j0 = (tid & 7) * 8;
    bf16x8 vvv = *(const bf16x8*)(V + (size_t)(rowbase + r) * 512 + h * 64 + j0);
#pragma unroll
    for (int u = 0; u < 8; u++) {
      int row = j0 + u;
      Vt[row * 64 + sw_t(row, r >> 3) + (r & 7)] = vvv[u];
    }
  }

  // prefix of chunk sums (bf16 states, fp32 accumulate): 16 elements/thread
  {
    float accp[16];
#pragma unroll
    for (int u = 0; u < 16; u++) accp[u] = 0.f;
    const bf16* base = KVs + ((size_t)(bh * NCHUNK) << 12) + tid * 16;
    for (int cc = 0; cc < chunk; cc++) {
      const bf16* pp = base + ((size_t)cc << 12);
      bf16x8 a0 = *(const bf16x8*)pp;
      bf16x8 a1 = *(const bf16x8*)(pp + 8);
#pragma unroll
      for (int u = 0; u < 8; u++) { accp[u] += (float)a0[u]; accp[8 + u] += (float)a1[u]; }
    }
    int j = tid >> 2, i0 = (tid & 3) * 16;
#pragma unroll
    for (int u = 0; u < 16; u++) {
      int i = i0 + u;
      Spre[j * 64 + sw_t(j, i >> 3) + (i & 7)] = (bf16)accp[u];
    }
  }

  // z prefix partials (per wave)
  {
    int i = tid & 63, qq = tid >> 6;
    float s = 0.f;
    for (int cc = qq; cc < chunk; cc += 4)
      s += zsum[(size_t)(bh * NCHUNK + cc) * 64 + i];
    zp4[qq][i] = s;
  }
  __syncthreads();  // B1: all LDS staged
  if (tid < 64) zpre[tid] = zp4[0][tid] + zp4[1][tid] + zp4[2][tid] + zp4[3][tid];

  // QK^T (all 4 n-frags; causal via ternary)
  f32x4 sacc[4] = {};
#pragma unroll
  for (int ks = 0; ks < 2; ks++) {
    int ar = 16 * wv + c;
    bf16x8 a = *(const bf16x8*)(Qs + ar * 64 + (((ks * 4 + quad) ^ (c & 7)) << 3));
#pragma unroll
    for (int j = 0; j < 4; j++) {
      int br = 16 * j + c;
      bf16x8 bb = *(const bf16x8*)(Ks + br * 64 + (((ks * 4 + quad) ^ (c & 7)) << 3));
      sacc[j] = __builtin_amdgcn_mfma_f32_16x16x32_bf16(a, bb, sacc[j], 0, 0, 0);
    }
  }

  // mask, rowsum, write As
  float rs[4] = {0.f, 0.f, 0.f, 0.f};
#pragma unroll
  for (int j = 0; j < 4; j++) {
#pragma unroll
    for (int r = 0; r < 4; r++) {
      int t = 16 * wv + quad * 4 + r, s = 16 * j + c;
      float v = (s <= t) ? sacc[j][r] : 0.f;
      rs[r] += v;
      As[t * 64 + sw_t(t, s >> 3) + (s & 7)] = (bf16)v;
    }
  }
#pragma unroll
  for (int r = 0; r < 4; r++) {
    float v = rs[r];
    v += __shfl_xor(v, 1); v += __shfl_xor(v, 2);
    v += __shfl_xor(v, 4); v += __shfl_xor(v, 8);
    if (c == 0) rsum[16 * wv + quad * 4 + r] = v;
  }
  __syncthreads();  // B2: As, rsum, zpre visible

  // den[t] = max(rowsum + Q[t].z_pre, 1e-6)
  if (tid < 64) {
    float s = rsum[tid];
    int t7 = tid & 7;
#pragma unroll
    for (int kg = 0; kg < 8; kg++) {
      bf16x8 qv = *(const bf16x8*)(Qs + tid * 64 + ((kg ^ t7) << 3));
#pragma unroll
      for (int u = 0; u < 8; u++) s += (float)qv[u] * zpre[kg * 8 + u];
    }
    den[tid] = fmaxf(s, 1e-6f);
  }

  // O = Q.S_pre + A.V
  f32x4 oacc[4] = {};
#pragma unroll
  for (int ks = 0; ks < 2; ks++) {
    int ar = 16 * wv + c;
    bf16x8 aq = *(const bf16x8*)(Qs + ar * 64 + (((ks * 4 + quad) ^ (c & 7)) << 3));
    bf16x8 aa = *(const bf16x8*)(As + ar * 64 + sw_t(ar, ks * 4 + quad));
#pragma unroll
    for (int j = 0; j < 4; j++) {
      int br = 16 * j + c;
      bf16x8 bs = *(const bf16x8*)(Spre + br * 64 + sw_t(br, ks * 4 + quad));
      bf16x8 bv = *(const bf16x8*)(Vt + br * 64 + sw_t(br, ks * 4 + quad));
      oacc[j] = __builtin_amdgcn_mfma_f32_16x16x32_bf16(aq, bs, oacc[j], 0, 0, 0);
      oacc[j] = __builtin_amdgcn_mfma_f32_16x16x32_bf16(aa, bv, oacc[j], 0, 0, 0);
    }
  }
  __syncthreads();  // B3: den visible
#pragma unroll
  for (int r = 0; r < 4; r++) {
    int t = 16 * wv + quad * 4 + r;
    float rd = 1.f / den[t];
#pragma unroll
    for (int j = 0; j < 4; j++)
      O[(size_t)(rowbase + t) * 512 + h * 64 + 16 * j + c] = (bf16)(oacc[j][r] * rd);
  }
}

extern "C" void kernel_launch(void* const* d_in, const int* in_sizes, int n_in,
                              void* d_out, int out_size, void* d_ws, size_t ws_size,
                              hipStream_t stream) {
  const float* x  = (const float*)d_in[0];
  const float* wq = (const float*)d_in[1];
  const float* wk = (const float*)d_in[2];
  const float* wv = (const float*)d_in[3];
  const float* wo = (const float*)d_in[4];
  float* out = (float*)d_out;

  char* p = (char*)d_ws;
  bf16* x_bf   = (bf16*)p; p += (size_t)MROWS * DMODEL * 2;
  bf16* wqkv_b = (bf16*)p; p += (size_t)3 * DMODEL * DMODEL * 2;
  bf16* wo_b   = (bf16*)p; p += (size_t)DMODEL * DMODEL * 2;
  bf16* Qb     = (bf16*)p; p += (size_t)MROWS * 512 * 2;
  bf16* Kb     = (bf16*)p; p += (size_t)MROWS * 512 * 2;
  bf16* Vb     = (bf16*)p; p += (size_t)MROWS * 512 * 2;
  bf16* Ob     = (bf16*)p; p += (size_t)MROWS * 512 * 2;
  bf16* KVs    = (bf16*)p; p += (size_t)BH * NCHUNK * DHEAD * DVAL * 2;
  float* zs    = (float*)p; p += (size_t)BH * NCHUNK * DHEAD * 4;

  k_convert<<<2048, 256, 0, stream>>>(x, wq, wk, wv, wo, x_bf, wqkv_b, wo_b);
  k_gemm<0><<<dim3(MROWS / 128, (3 * DMODEL) / 128), 256, 0, stream>>>(
      x_bf, wqkv_b, Qb, Kb, Vb, nullptr);
  k_state<<<dim3(NCHUNK, BH), 256, 0, stream>>>(Kb, Vb, KVs, zs);
  k_attn<<<dim3(NCHUNK, BH), 256, 0, stream>>>(Qb, Kb, Vb, KVs, zs, Ob);
  k_gemm<1><<<dim3(MROWS / 128, DMODEL / 128), 256, 0, stream>>>(
      Ob, wo_b, nullptr, nullptr, nullptr, out);
}